// Round 7
// baseline (124.024 us; speedup 1.0000x reference)
//
#include <hip/hip_runtime.h>
#include <hip/hip_bf16.h>
#include <math.h>

// Problem constants
#define N 2048
#define NFEAT 128
#define NHID 32
#define NCLASS 16
#define NSTRIP 32          // K-split factor for the two N x N GEMMs
#define KS 64              // strip width = N / NSTRIP

// ws layout (float elements)
#define WS_T1    0                         // [2048][32]
#define WS_Y0    65536                     // [2048][16]
#define WS_WA    98304                     // [32]
#define WS_WB    98336                     // [32]
#define WS_CB    98368                     // [1] (+pad)
#define WS_PART2 98432                     // [32][2048][32]
#define WS_Y     2195584                   // [2048][16]
#define WS_PC    2228352                   // [2048]
#define WS_Q     2230400                   // [2048]
#define WS_PART3 2232448                   // [32][2048][16]
// total 3281024 floats = 13.1 MB

// ---------------------------------------------------------------------------
// K1: t1 = x_init @ W1 ; y0 = x_init @ W2[32:160] ; block0 computes wa,wb,cb
// ---------------------------------------------------------------------------
__global__ __launch_bounds__(256) void k1_prep(
    const float* __restrict__ x_init, const float* __restrict__ W1,
    const float* __restrict__ W2, const float* __restrict__ Wc1,
    const float* __restrict__ bc1, const float* __restrict__ Wc2,
    const float* __restrict__ bc2, float* __restrict__ ws)
{
    __shared__ float xs[8 * 128];
    __shared__ float W1s[128 * 32];
    __shared__ float W2bs[128 * 16];
    int t = threadIdx.x;
    int blk = blockIdx.x;

    // vectorized staging
    *reinterpret_cast<float4*>(&xs[4 * t]) =
        *reinterpret_cast<const float4*>(&x_init[blk * 1024 + 4 * t]);
    #pragma unroll
    for (int i = 0; i < 4; ++i) {
        int f = t + 256 * i;
        *reinterpret_cast<float4*>(&W1s[4 * f]) =
            *reinterpret_cast<const float4*>(&W1[4 * f]);
    }
    #pragma unroll
    for (int i = 0; i < 2; ++i) {
        int f = t + 256 * i;
        *reinterpret_cast<float4*>(&W2bs[4 * f]) =
            *reinterpret_cast<const float4*>(&W2[512 + 4 * f]);
    }
    __syncthreads();

    int rl = t >> 5, c = t & 31;
    int r = blk * 8 + rl;

    float acc = 0.f;
    #pragma unroll 8
    for (int k = 0; k < 128; ++k) acc = fmaf(xs[rl * 128 + k], W1s[k * 32 + c], acc);
    ws[WS_T1 + r * 32 + c] = acc;

    if (c < 16) {
        float a2 = 0.f;
        #pragma unroll 8
        for (int k = 0; k < 128; ++k) a2 = fmaf(xs[rl * 128 + k], W2bs[k * 16 + c], a2);
        ws[WS_Y0 + r * 16 + c] = a2;
    }

    if (blk == 0 && t < 32) {
        float wa = 0.f, wb = 0.f;
        for (int h = 0; h < 32; ++h) {
            float w = Wc2[h];
            wa = fmaf(Wc1[t * 32 + h], w, wa);
            wb = fmaf(Wc1[(32 + t) * 32 + h], w, wb);
        }
        ws[WS_WA + t] = wa;
        ws[WS_WB + t] = wb;
        if (t == 0) {
            float cb = bc2[0];
            for (int h = 0; h < 32; ++h) cb = fmaf(bc1[h], Wc2[h], cb);
            ws[WS_CB] = cb;
        }
    }
}

// ---------------------------------------------------------------------------
// K2: partial2[ks][r][c] = sum_{j in ks-strip} adj[r,j] * t1[j,c]
// BM=128 x BK=64 x BN=32; grid = 16 rowtiles x 32 strips = 512 (2/CU)
// thread (rg = t>>3 in 0..31, cg = t&7): rows {rg+32i}, cols 4cg..4cg+3
// A tile XOR-swizzled in 16B units: unit' = unit ^ (row&7)  (conflict-free:
// each a-read instr touches 8 consecutive rows -> 8 distinct bank quads)
// ---------------------------------------------------------------------------
__global__ __launch_bounds__(256, 2) void k2_mm(
    const float* __restrict__ A, const float* __restrict__ ws_in,
    float* __restrict__ ws_out)
{
    __shared__ float As[128 * 64];     // swizzled, no pad
    __shared__ float Bs[64 * 32];

    const float* t1 = ws_in + WS_T1;
    int t = threadIdx.x;
    int rt = blockIdx.x >> 5;          // 0..15 row tile
    int ks = blockIdx.x & 31;          // 0..31 K strip
    int row0 = rt * 128;
    int jbase = ks * KS;

    // stage A strip: 128 rows x 64 cols, coalesced float4, swizzled store
    #pragma unroll
    for (int i = 0; i < 8; ++i) {
        int f = t + 256 * i;                   // 0..2047 float4 units
        int r = f >> 4, u = f & 15;
        float4 v = *reinterpret_cast<const float4*>(
            &A[(size_t)(row0 + r) * N + jbase + 4 * u]);
        *reinterpret_cast<float4*>(&As[4 * (r * 16 + (u ^ (r & 7)))]) = v;
    }
    // stage B strip: t1 rows jbase..jbase+63 (64 x 32), linear
    #pragma unroll
    for (int i = 0; i < 2; ++i) {
        int f = t + 256 * i;                   // 0..511
        int r = f >> 3, c4 = f & 7;
        float4 v = *reinterpret_cast<const float4*>(&t1[(jbase + r) * 32 + 4 * c4]);
        *reinterpret_cast<float4*>(&Bs[r * 32 + 4 * c4]) = v;
    }
    __syncthreads();

    int rg = t >> 3;                   // 0..31
    int cg = t & 7;                    // 0..7
    int rsw = rg & 7;                  // (rg+32i)&7 == rg&7

    float acc0[4] = {0.f, 0.f, 0.f, 0.f};
    float acc1[4] = {0.f, 0.f, 0.f, 0.f};
    float acc2[4] = {0.f, 0.f, 0.f, 0.f};
    float acc3[4] = {0.f, 0.f, 0.f, 0.f};

    #pragma unroll
    for (int kq = 0; kq < 16; ++kq) {
        int ku = kq ^ rsw;
        float4 a0 = *reinterpret_cast<const float4*>(&As[4 * ((rg +  0) * 16 + ku)]);
        float4 a1 = *reinterpret_cast<const float4*>(&As[4 * ((rg + 32) * 16 + ku)]);
        float4 a2 = *reinterpret_cast<const float4*>(&As[4 * ((rg + 64) * 16 + ku)]);
        float4 a3 = *reinterpret_cast<const float4*>(&As[4 * ((rg + 96) * 16 + ku)]);
        float4 b0 = *reinterpret_cast<const float4*>(&Bs[(4 * kq + 0) * 32 + 4 * cg]);
        float4 b1 = *reinterpret_cast<const float4*>(&Bs[(4 * kq + 1) * 32 + 4 * cg]);
        float4 b2 = *reinterpret_cast<const float4*>(&Bs[(4 * kq + 2) * 32 + 4 * cg]);
        float4 b3 = *reinterpret_cast<const float4*>(&Bs[(4 * kq + 3) * 32 + 4 * cg]);

        acc0[0] = fmaf(a0.x, b0.x, acc0[0]); acc0[1] = fmaf(a0.x, b0.y, acc0[1]);
        acc0[2] = fmaf(a0.x, b0.z, acc0[2]); acc0[3] = fmaf(a0.x, b0.w, acc0[3]);
        acc0[0] = fmaf(a0.y, b1.x, acc0[0]); acc0[1] = fmaf(a0.y, b1.y, acc0[1]);
        acc0[2] = fmaf(a0.y, b1.z, acc0[2]); acc0[3] = fmaf(a0.y, b1.w, acc0[3]);
        acc0[0] = fmaf(a0.z, b2.x, acc0[0]); acc0[1] = fmaf(a0.z, b2.y, acc0[1]);
        acc0[2] = fmaf(a0.z, b2.z, acc0[2]); acc0[3] = fmaf(a0.z, b2.w, acc0[3]);
        acc0[0] = fmaf(a0.w, b3.x, acc0[0]); acc0[1] = fmaf(a0.w, b3.y, acc0[1]);
        acc0[2] = fmaf(a0.w, b3.z, acc0[2]); acc0[3] = fmaf(a0.w, b3.w, acc0[3]);

        acc1[0] = fmaf(a1.x, b0.x, acc1[0]); acc1[1] = fmaf(a1.x, b0.y, acc1[1]);
        acc1[2] = fmaf(a1.x, b0.z, acc1[2]); acc1[3] = fmaf(a1.x, b0.w, acc1[3]);
        acc1[0] = fmaf(a1.y, b1.x, acc1[0]); acc1[1] = fmaf(a1.y, b1.y, acc1[1]);
        acc1[2] = fmaf(a1.y, b1.z, acc1[2]); acc1[3] = fmaf(a1.y, b1.w, acc1[3]);
        acc1[0] = fmaf(a1.z, b2.x, acc1[0]); acc1[1] = fmaf(a1.z, b2.y, acc1[1]);
        acc1[2] = fmaf(a1.z, b2.z, acc1[2]); acc1[3] = fmaf(a1.z, b2.w, acc1[3]);
        acc1[0] = fmaf(a1.w, b3.x, acc1[0]); acc1[1] = fmaf(a1.w, b3.y, acc1[1]);
        acc1[2] = fmaf(a1.w, b3.z, acc1[2]); acc1[3] = fmaf(a1.w, b3.w, acc1[3]);

        acc2[0] = fmaf(a2.x, b0.x, acc2[0]); acc2[1] = fmaf(a2.x, b0.y, acc2[1]);
        acc2[2] = fmaf(a2.x, b0.z, acc2[2]); acc2[3] = fmaf(a2.x, b0.w, acc2[3]);
        acc2[0] = fmaf(a2.y, b1.x, acc2[0]); acc2[1] = fmaf(a2.y, b1.y, acc2[1]);
        acc2[2] = fmaf(a2.y, b1.z, acc2[2]); acc2[3] = fmaf(a2.y, b1.w, acc2[3]);
        acc2[0] = fmaf(a2.z, b2.x, acc2[0]); acc2[1] = fmaf(a2.z, b2.y, acc2[1]);
        acc2[2] = fmaf(a2.z, b2.z, acc2[2]); acc2[3] = fmaf(a2.z, b2.w, acc2[3]);
        acc2[0] = fmaf(a2.w, b3.x, acc2[0]); acc2[1] = fmaf(a2.w, b3.y, acc2[1]);
        acc2[2] = fmaf(a2.w, b3.z, acc2[2]); acc2[3] = fmaf(a2.w, b3.w, acc2[3]);

        acc3[0] = fmaf(a3.x, b0.x, acc3[0]); acc3[1] = fmaf(a3.x, b0.y, acc3[1]);
        acc3[2] = fmaf(a3.x, b0.z, acc3[2]); acc3[3] = fmaf(a3.x, b0.w, acc3[3]);
        acc3[0] = fmaf(a3.y, b1.x, acc3[0]); acc3[1] = fmaf(a3.y, b1.y, acc3[1]);
        acc3[2] = fmaf(a3.y, b1.z, acc3[2]); acc3[3] = fmaf(a3.y, b1.w, acc3[3]);
        acc3[0] = fmaf(a3.z, b2.x, acc3[0]); acc3[1] = fmaf(a3.z, b2.y, acc3[1]);
        acc3[2] = fmaf(a3.z, b2.z, acc3[2]); acc3[3] = fmaf(a3.z, b2.w, acc3[3]);
        acc3[0] = fmaf(a3.w, b3.x, acc3[0]); acc3[1] = fmaf(a3.w, b3.y, acc3[1]);
        acc3[2] = fmaf(a3.w, b3.z, acc3[2]); acc3[3] = fmaf(a3.w, b3.w, acc3[3]);
    }

    float* base = ws_out + WS_PART2 + ((size_t)ks * N) * 32 + 4 * cg;
    *reinterpret_cast<float4*>(base + (size_t)(row0 + rg +  0) * 32) =
        make_float4(acc0[0], acc0[1], acc0[2], acc0[3]);
    *reinterpret_cast<float4*>(base + (size_t)(row0 + rg + 32) * 32) =
        make_float4(acc1[0], acc1[1], acc1[2], acc1[3]);
    *reinterpret_cast<float4*>(base + (size_t)(row0 + rg + 64) * 32) =
        make_float4(acc2[0], acc2[1], acc2[2], acc2[3]);
    *reinterpret_cast<float4*>(base + (size_t)(row0 + rg + 96) * 32) =
        make_float4(acc3[0], acc3[1], acc3[2], acc3[3]);
}

// ---------------------------------------------------------------------------
// K2b: x = tanh(sum partials + b1); p,q row scalars; y = x@W2[:32] + y0
// ---------------------------------------------------------------------------
__global__ __launch_bounds__(256) void k2b_post(
    const float* __restrict__ b1, const float* __restrict__ W2,
    float* __restrict__ ws)
{
    __shared__ float xs[8][32];
    int t = threadIdx.x;
    int rl = t >> 5, c = t & 31;
    int r = blockIdx.x * 8 + rl;

    const float* p2 = ws + WS_PART2;
    float s = b1[c];
    #pragma unroll
    for (int ks = 0; ks < NSTRIP; ++ks)
        s += p2[(size_t)(ks * N + r) * 32 + c];
    float x = tanhf(s);
    xs[rl][c] = x;
    __syncthreads();

    float pp = x * ws[WS_WA + c];
    float qq = x * ws[WS_WB + c];
    #pragma unroll
    for (int d = 1; d < 32; d <<= 1) {
        pp += __shfl_xor(pp, d);
        qq += __shfl_xor(qq, d);
    }
    if (c == 0) {
        ws[WS_PC + r] = pp + ws[WS_CB];
        ws[WS_Q + r] = qq;
    }

    if (c < 16) {
        float acc = ws[WS_Y0 + r * 16 + c];
        #pragma unroll 8
        for (int h = 0; h < 32; ++h) acc = fmaf(xs[rl][h], W2[h * 16 + c], acc);
        ws[WS_Y + r * 16 + c] = acc;
    }
}

// ---------------------------------------------------------------------------
// K3: partial3[ks][r][c] = sum_{j in strip} adj[r,j]*score(pc[r]+q[j])*y[j,c]
// BM=128 x BK=64 x BN=16; grid 512; score fused into A staging
// thread (rg = t>>2 in 0..63, cg = t&3): rows {rg, rg+64}, cols 4cg..4cg+3
// Same XOR swizzle on A (16 consecutive rows/instr -> 2-way = free)
// ---------------------------------------------------------------------------
__global__ __launch_bounds__(256, 2) void k3_mm(
    const float* __restrict__ A, const float* __restrict__ ws_in,
    float* __restrict__ ws_out)
{
    __shared__ float As[128 * 64];
    __shared__ float Bs[64 * 16];

    const float* y = ws_in + WS_Y;
    const float* qv = ws_in + WS_Q;
    const float* pc = ws_in + WS_PC;
    int t = threadIdx.x;
    int rt = blockIdx.x >> 5;
    int ks = blockIdx.x & 31;
    int row0 = rt * 128;
    int jbase = ks * KS;

    // stage A strip with fused score transform, swizzled store
    #pragma unroll
    for (int i = 0; i < 8; ++i) {
        int f = t + 256 * i;
        int r = f >> 4, u = f & 15;
        int j0 = jbase + 4 * u;
        float4 a = *reinterpret_cast<const float4*>(&A[(size_t)(row0 + r) * N + j0]);
        float4 q4 = *reinterpret_cast<const float4*>(&qv[j0]);
        float pcr = pc[row0 + r];
        float e0 = pcr + q4.x, e1 = pcr + q4.y, e2 = pcr + q4.z, e3 = pcr + q4.w;
        float4 cf;
        cf.x = a.x * ((e0 > 0.f) ? 1.f : e0);
        cf.y = a.y * ((e1 > 0.f) ? 1.f : e1);
        cf.z = a.z * ((e2 > 0.f) ? 1.f : e2);
        cf.w = a.w * ((e3 > 0.f) ? 1.f : e3);
        *reinterpret_cast<float4*>(&As[4 * (r * 16 + (u ^ (r & 7)))]) = cf;
    }
    // stage y strip: 64 x 16, linear
    {
        int r = t >> 2, c4 = t & 3;
        float4 v = *reinterpret_cast<const float4*>(&y[(jbase + r) * 16 + 4 * c4]);
        *reinterpret_cast<float4*>(&Bs[r * 16 + 4 * c4]) = v;
    }
    __syncthreads();

    int rg = t >> 2;                   // 0..63
    int cg = t & 3;                    // 0..3
    int rsw = rg & 7;                  // (rg+64)&7 == rg&7

    float acc0[4] = {0.f, 0.f, 0.f, 0.f};
    float acc1[4] = {0.f, 0.f, 0.f, 0.f};

    #pragma unroll
    for (int kq = 0; kq < 16; ++kq) {
        int ku = kq ^ rsw;
        float4 a0 = *reinterpret_cast<const float4*>(&As[4 * ((rg +  0) * 16 + ku)]);
        float4 a1 = *reinterpret_cast<const float4*>(&As[4 * ((rg + 64) * 16 + ku)]);
        float4 b0 = *reinterpret_cast<const float4*>(&Bs[(4 * kq + 0) * 16 + 4 * cg]);
        float4 b1 = *reinterpret_cast<const float4*>(&Bs[(4 * kq + 1) * 16 + 4 * cg]);
        float4 b2 = *reinterpret_cast<const float4*>(&Bs[(4 * kq + 2) * 16 + 4 * cg]);
        float4 b3 = *reinterpret_cast<const float4*>(&Bs[(4 * kq + 3) * 16 + 4 * cg]);

        acc0[0] = fmaf(a0.x, b0.x, acc0[0]); acc0[1] = fmaf(a0.x, b0.y, acc0[1]);
        acc0[2] = fmaf(a0.x, b0.z, acc0[2]); acc0[3] = fmaf(a0.x, b0.w, acc0[3]);
        acc0[0] = fmaf(a0.y, b1.x, acc0[0]); acc0[1] = fmaf(a0.y, b1.y, acc0[1]);
        acc0[2] = fmaf(a0.y, b1.z, acc0[2]); acc0[3] = fmaf(a0.y, b1.w, acc0[3]);
        acc0[0] = fmaf(a0.z, b2.x, acc0[0]); acc0[1] = fmaf(a0.z, b2.y, acc0[1]);
        acc0[2] = fmaf(a0.z, b2.z, acc0[2]); acc0[3] = fmaf(a0.z, b2.w, acc0[3]);
        acc0[0] = fmaf(a0.w, b3.x, acc0[0]); acc0[1] = fmaf(a0.w, b3.y, acc0[1]);
        acc0[2] = fmaf(a0.w, b3.z, acc0[2]); acc0[3] = fmaf(a0.w, b3.w, acc0[3]);

        acc1[0] = fmaf(a1.x, b0.x, acc1[0]); acc1[1] = fmaf(a1.x, b0.y, acc1[1]);
        acc1[2] = fmaf(a1.x, b0.z, acc1[2]); acc1[3] = fmaf(a1.x, b0.w, acc1[3]);
        acc1[0] = fmaf(a1.y, b1.x, acc1[0]); acc1[1] = fmaf(a1.y, b1.y, acc1[1]);
        acc1[2] = fmaf(a1.y, b1.z, acc1[2]); acc1[3] = fmaf(a1.y, b1.w, acc1[3]);
        acc1[0] = fmaf(a1.z, b2.x, acc1[0]); acc1[1] = fmaf(a1.z, b2.y, acc1[1]);
        acc1[2] = fmaf(a1.z, b2.z, acc1[2]); acc1[3] = fmaf(a1.z, b2.w, acc1[3]);
        acc1[0] = fmaf(a1.w, b3.x, acc1[0]); acc1[1] = fmaf(a1.w, b3.y, acc1[1]);
        acc1[2] = fmaf(a1.w, b3.z, acc1[2]); acc1[3] = fmaf(a1.w, b3.w, acc1[3]);
    }

    float* base = ws_out + WS_PART3 + ((size_t)ks * N) * 16 + 4 * cg;
    *reinterpret_cast<float4*>(base + (size_t)(row0 + rg +  0) * 16) =
        make_float4(acc0[0], acc0[1], acc0[2], acc0[3]);
    *reinterpret_cast<float4*>(base + (size_t)(row0 + rg + 64) * 16) =
        make_float4(acc1[0], acc1[1], acc1[2], acc1[3]);
}

// ---------------------------------------------------------------------------
// K3b: out[r] = log_softmax(sum partials + b2)
// ---------------------------------------------------------------------------
__global__ __launch_bounds__(256) void k3b_lsm(
    const float* __restrict__ b2, const float* __restrict__ ws,
    float* __restrict__ out)
{
    int t = threadIdx.x;
    int rl = t >> 4, c = t & 15;
    int r = blockIdx.x * 16 + rl;

    const float* p3 = ws + WS_PART3;
    float o = b2[c];
    #pragma unroll
    for (int ks = 0; ks < NSTRIP; ++ks)
        o += p3[(size_t)(ks * N + r) * 16 + c];

    float m = o;
    #pragma unroll
    for (int d = 1; d < 16; d <<= 1) m = fmaxf(m, __shfl_xor(m, d));
    float ex = expf(o - m);
    float sm = ex;
    #pragma unroll
    for (int d = 1; d < 16; d <<= 1) sm += __shfl_xor(sm, d);

    out[r * 16 + c] = o - m - logf(sm);
}

// ---------------------------------------------------------------------------
extern "C" void kernel_launch(void* const* d_in, const int* in_sizes, int n_in,
                              void* d_out, int out_size, void* d_ws, size_t ws_size,
                              hipStream_t stream)
{
    const float* x_init = (const float*)d_in[0];
    // d_in[1] adj: unused by the reference
    const float* adj1   = (const float*)d_in[2];
    // d_in[3] fully_connected_graph: unused
    const float* W1  = (const float*)d_in[4];
    const float* b1  = (const float*)d_in[5];
    const float* W2  = (const float*)d_in[6];
    const float* b2  = (const float*)d_in[7];
    const float* Wc1 = (const float*)d_in[8];
    const float* bc1 = (const float*)d_in[9];
    const float* Wc2 = (const float*)d_in[10];
    const float* bc2 = (const float*)d_in[11];
    float* out = (float*)d_out;
    float* ws = (float*)d_ws;

    hipLaunchKernelGGL(k1_prep, dim3(256), dim3(256), 0, stream,
                       x_init, W1, W2, Wc1, bc1, Wc2, bc2, ws);
    hipLaunchKernelGGL(k2_mm, dim3(512), dim3(256), 0, stream, adj1, ws, ws);
    hipLaunchKernelGGL(k2b_post, dim3(256), dim3(256), 0, stream, b1, W2, ws);
    hipLaunchKernelGGL(k3_mm, dim3(512), dim3(256), 0, stream, adj1, ws, ws);
    hipLaunchKernelGGL(k3b_lsm, dim3(128), dim3(256), 0, stream, b2, ws, out);
}